// Round 8
// baseline (221.280 us; speedup 1.0000x reference)
//
#include <hip/hip_runtime.h>

#define C_OUT  32
#define PS     16
#define KB     288          // 3*3*32 input capsules per patch
#define NITER  3
#define EPSL   1e-6f
#define LAM    0.001f
#define OH     12
#define OW     12
#define NPOS   576          // 4*12*12
#define MU_SZ  (NPOS*C_OUT*PS)
#define NG     16           // k-groups (one per 32-lane half-wave)
#define KPG    (KB/NG)      // 18 k's per thread
#define LOG2E  1.44269504088896340736f

// v[k,c,i,l] = sum_j xp[k,i,j] * w[k,c,j,l]  — full 4x4 matrix per (k,c) in registers.
__device__ __forceinline__ void compute_v(const float* __restrict__ xp,
                                          const float* __restrict__ w,
                                          int k, int c, float* __restrict__ va) {
    const float4* xk = (const float4*)(xp + (k << 4));
    float4 x0 = xk[0], x1 = xk[1], x2 = xk[2], x3 = xk[3];   // row i over j
    const float4* wr = (const float4*)(w + (((k << 5) + c) << 4));
    float4 w0 = wr[0], w1 = wr[1], w2 = wr[2], w3 = wr[3];   // row j over l
#define VROW(i, xi) \
    va[4*i+0] = fmaf(xi.x, w0.x, fmaf(xi.y, w1.x, fmaf(xi.z, w2.x, xi.w * w3.x))); \
    va[4*i+1] = fmaf(xi.x, w0.y, fmaf(xi.y, w1.y, fmaf(xi.z, w2.y, xi.w * w3.y))); \
    va[4*i+2] = fmaf(xi.x, w0.z, fmaf(xi.y, w1.z, fmaf(xi.z, w2.z, xi.w * w3.z))); \
    va[4*i+3] = fmaf(xi.x, w0.w, fmaf(xi.y, w1.w, fmaf(xi.z, w2.w, xi.w * w3.w)));
    VROW(0, x0) VROW(1, x1) VROW(2, x2) VROW(3, x3)
#undef VROW
}

// (512,2): let the allocator take ~116 VGPR with zero spill (forcing more
// occupancy spilled 1.5 GB to scratch in earlier rounds).
__global__ __launch_bounds__(512, 2)
void emcaps_kernel(const float* __restrict__ x, const float* __restrict__ a,
                   const float* __restrict__ w, const float* __restrict__ beta_u,
                   const float* __restrict__ beta_a, float* __restrict__ out) {
    __shared__ __align__(16) float xp[KB * PS];   // 18 KB patch poses [k][16]
    __shared__ float a_lds[KB];                   // input activations (pre-scaled 1/C)
    __shared__ float lnb[KB][33];                 // 38 KB ln/e-values; col 32 = 1/sum
    __shared__ float buf[8][32][16];              // 16 KB m1-then-m2 partial rounds
    __shared__ float rsp[8][32];                  // partial r_sum
    __shared__ float mu_s[32][16];                // mu [c][e ^ (c&15)]
    __shared__ float is_s[32][16];                // (0.5/sig^2)*LOG2E, same swizzle
    __shared__ float cst_s[32];                   // (log(ao) - hl)*LOG2E
    __shared__ float ao_s[32];                    // a_out of previous iteration

    const int t  = threadIdx.x;       // 512 threads
    const int g  = t >> 5;            // k-group 0..15  (E-step view)
    const int c  = t & 31;            // output capsule (E-step view)
    const int oc = t >> 4;            // capsule 0..31  (M-step view)
    const int oe = t & 15;            // pose elem      (M-step view)

    const int pos = blockIdx.x;
    const int bb  = pos / (OH * OW);
    const int rem = pos % (OH * OW);
    const int hh  = rem / OW;
    const int ww  = rem % OW;

    // ---- stage 3x3 patch into LDS (9 contiguous 2 KB rows, coalesced float4)
    const float4* x4  = (const float4*)x;
    float4*       xp4 = (float4*)xp;
    for (int u = t; u < KB * PS / 4; u += 512) {
        int pc = u >> 7, r = u & 127;
        int ki = pc / 3, kj = pc % 3;
        long src = (((long)(bb * 14 + hh + ki)) * 14 + (ww + kj)) * 128;
        xp4[u] = x4[src + r];
    }
    if (t < KB) {
        int pc = t >> 5, bi = t & 31;
        int ki = pc / 3, kj = pc % 3;
        a_lds[t] = a[(((bb * 14 + hh + ki)) * 14 + (ww + kj)) * 32 + bi] * (1.0f / C_OUT);
    }
    __syncthreads();

    const float buC = beta_u[oc];
    const float baC = beta_a[oc];

    float muR[16], isR[16];           // E-step per-c state (registers)
    float cstC = 0.f;

    for (int it = 0; it < NITER; ++it) {
        float m1[16], m2[16], rs = 0.f;

        if (it == 0) {
            #pragma unroll
            for (int e = 0; e < 16; ++e) { m1[e] = 0.f; m2[e] = 0.f; }
            #pragma unroll 2
            for (int kk = 0; kk < KPG; ++kk) {
                int k = g * KPG + kk;
                float va[16];
                compute_v(xp, w, k, c, va);
                float r = a_lds[k];               // already scaled by 1/C
                rs += r;
                #pragma unroll
                for (int e = 0; e < 16; ++e) {
                    float rv = r * va[e];
                    m1[e] += rv;
                    m2[e] = fmaf(rv, va[e], m2[e]);
                }
            }
        } else {
            // ---- P1: ln(k,c) for all k (lane-local, no cross-lane ops)
            #pragma unroll 2
            for (int kk = 0; kk < KPG; ++kk) {
                int k = g * KPG + kk;
                float va[16];
                compute_v(xp, w, k, c, va);
                float acc = 0.f;
                #pragma unroll
                for (int e = 0; e < 16; ++e) {
                    float d = va[e] - muR[e];
                    acc = fmaf(d * isR[e], d, acc);   // log2-domain (isR pre-scaled)
                }
                lnb[k][c] = cstC - acc;
            }
            __syncthreads();
            // ---- P2: transposed softmax — thread t owns k=t, all 32 c's in-lane
            if (t < KB) {
                const float* row = lnb[t];
                float a0 = row[0], a1 = row[1], a2 = row[2], a3 = row[3];
                #pragma unroll
                for (int j = 4; j < 32; j += 4) {
                    a0 = fmaxf(a0, row[j]);
                    a1 = fmaxf(a1, row[j + 1]);
                    a2 = fmaxf(a2, row[j + 2]);
                    a3 = fmaxf(a3, row[j + 3]);
                }
                float mx = fmaxf(fmaxf(a0, a1), fmaxf(a2, a3));
                float s0 = 0.f, s1 = 0.f, s2 = 0.f, s3 = 0.f;
                #pragma unroll
                for (int j = 0; j < 32; j += 4) {
                    float e0 = exp2f(row[j]     - mx);
                    float e1 = exp2f(row[j + 1] - mx);
                    float e2 = exp2f(row[j + 2] - mx);
                    float e3 = exp2f(row[j + 3] - mx);
                    lnb[t][j]     = e0;  s0 += e0;
                    lnb[t][j + 1] = e1;  s1 += e1;
                    lnb[t][j + 2] = e2;  s2 += e2;
                    lnb[t][j + 3] = e3;  s3 += e3;
                }
                lnb[t][32] = __builtin_amdgcn_rcpf((s0 + s1) + (s2 + s3));
            }
            __syncthreads();
            // ---- P3: recompute v, accumulate moments with r' (a_out factored out)
            #pragma unroll
            for (int e = 0; e < 16; ++e) { m1[e] = 0.f; m2[e] = 0.f; }
            #pragma unroll 2
            for (int kk = 0; kk < KPG; ++kk) {
                int k = g * KPG + kk;
                float va[16];
                compute_v(xp, w, k, c, va);
                float rp = lnb[k][c] * lnb[k][32];
                rs += rp;
                #pragma unroll
                for (int e = 0; e < 16; ++e) {
                    float rv = rp * va[e];
                    m1[e] += rv;
                    m2[e] = fmaf(rv, va[e], m2[e]);
                }
            }
        }

        // ---- reduce over g: in-wave pair reduce, then two-round LDS tree
        rs += __shfl_xor(rs, 32);
        #pragma unroll
        for (int e = 0; e < 16; ++e) m1[e] += __shfl_xor(m1[e], 32);
        #pragma unroll
        for (int e = 0; e < 16; ++e) m2[e] += __shfl_xor(m2[e], 32);

        if ((g & 1) == 0) {                       // round A: m1 + rs
            int gp = g >> 1;
            #pragma unroll
            for (int e = 0; e < 16; ++e) buf[gp][c][e ^ (c & 15)] = m1[e];
            rsp[gp][c] = rs;
        }
        __syncthreads();
        float M1 = 0.f, RS = 0.f;
        #pragma unroll
        for (int gp = 0; gp < 8; ++gp) M1 += buf[gp][oc][oe ^ (oc & 15)];
        #pragma unroll
        for (int gp = 0; gp < 8; ++gp) RS += rsp[gp][oc];
        __syncthreads();                          // m1 reads done before m2 overwrite
        if ((g & 1) == 0) {                       // round B: m2
            int gp = g >> 1;
            #pragma unroll
            for (int e = 0; e < 16; ++e) buf[gp][c][e ^ (c & 15)] = m2[e];
        }
        __syncthreads();
        float M2 = 0.f;
        #pragma unroll
        for (int gp = 0; gp < 8; ++gp) M2 += buf[gp][oc][oe ^ (oc & 15)];

        // ---- M-step (oc, oe view); re-apply a_out factor for it>0
        if (it > 0) {
            float ao_p = ao_s[oc];
            M1 *= ao_p; M2 *= ao_p; RS *= ao_p;
        }
        float inv = __builtin_amdgcn_rcpf(RS + EPSL);
        float muv = M1 * inv;
        float s   = RS * inv;
        float sig = fmaf(-muv * muv, (2.0f - s), M2 * inv) + EPSL;
        float hl  = 0.5f * __logf(sig);           // natural log (for cost)
        hl += __shfl_xor(hl, 1);
        hl += __shfl_xor(hl, 2);
        hl += __shfl_xor(hl, 4);
        hl += __shfl_xor(hl, 8);
        float cost = RS * fmaf(16.0f, buC, hl);
        float ao   = 1.0f / (1.0f + __expf(-LAM * (baC - cost)));

        if (it == NITER - 1) {
            out[pos * 512 + t] = muv;                    // t == oc*16+oe
            if (oe == 0) out[MU_SZ + pos * 32 + oc] = ao;
        } else {
            mu_s[oc][oe ^ (oc & 15)] = muv;
            is_s[oc][oe ^ (oc & 15)] = (0.5f / sig) * LOG2E;
            if (oe == 0) {
                cst_s[oc] = (__logf(ao) - hl) * LOG2E;
                ao_s[oc]  = ao;
            }
            __syncthreads();
            // back in (g,c) view: pull next-iteration E-state into registers
            #pragma unroll
            for (int e = 0; e < 16; ++e) muR[e] = mu_s[c][e ^ (c & 15)];
            #pragma unroll
            for (int e = 0; e < 16; ++e) isR[e] = is_s[c][e ^ (c & 15)];
            cstC = cst_s[c];
        }
    }
}

extern "C" void kernel_launch(void* const* d_in, const int* in_sizes, int n_in,
                              void* d_out, int out_size, void* d_ws, size_t ws_size,
                              hipStream_t stream) {
    const float* x  = (const float*)d_in[0];
    const float* a  = (const float*)d_in[1];
    const float* w  = (const float*)d_in[2];
    const float* bu = (const float*)d_in[3];
    const float* ba = (const float*)d_in[4];
    float* out = (float*)d_out;
    emcaps_kernel<<<NPOS, 512, 0, stream>>>(x, a, w, bu, ba, out);
}

// Round 9
// 169.683 us; speedup vs baseline: 1.3041x; 1.3041x over previous
//
#include <hip/hip_runtime.h>

#define C_OUT  32
#define PS     16
#define KB     288          // 3*3*32 input capsules per patch
#define NITER  3
#define EPSL   1e-6f
#define LAM    0.001f
#define OH     12
#define OW     12
#define NPOS   576          // 4*12*12
#define MU_SZ  (NPOS*C_OUT*PS)
#define NG     16           // k-groups (one per 32-lane half-wave)
#define KPG    (KB/NG)      // 18 k's per thread
#define LOG2E  1.44269504088896340736f

// v[k,c,i,l] = sum_j xp[k,i,j] * w[k,c,j,l]  — full 4x4 matrix per (k,c) in registers.
__device__ __forceinline__ void compute_v(const float* __restrict__ xp,
                                          const float* __restrict__ w,
                                          int k, int c, float* __restrict__ va) {
    const float4* xk = (const float4*)(xp + (k << 4));
    float4 x0 = xk[0], x1 = xk[1], x2 = xk[2], x3 = xk[3];   // row i over j
    const float4* wr = (const float4*)(w + (((k << 5) + c) << 4));
    float4 w0 = wr[0], w1 = wr[1], w2 = wr[2], w3 = wr[3];   // row j over l
#define VROW(i, xi) \
    va[4*i+0] = fmaf(xi.x, w0.x, fmaf(xi.y, w1.x, fmaf(xi.z, w2.x, xi.w * w3.x))); \
    va[4*i+1] = fmaf(xi.x, w0.y, fmaf(xi.y, w1.y, fmaf(xi.z, w2.y, xi.w * w3.y))); \
    va[4*i+2] = fmaf(xi.x, w0.z, fmaf(xi.y, w1.z, fmaf(xi.z, w2.z, xi.w * w3.z))); \
    va[4*i+3] = fmaf(xi.x, w0.w, fmaf(xi.y, w1.w, fmaf(xi.z, w2.w, xi.w * w3.w)));
    VROW(0, x0) VROW(1, x1) VROW(2, x2) VROW(3, x3)
#undef VROW
}

// (512,2): allocator takes ~116 VGPR with zero spill. Forcing higher occupancy
// spilled 1.5 GB to scratch (rounds 2-3). Must stay <=128 VGPR (wave cliff).
__global__ __launch_bounds__(512, 2)
void emcaps_kernel(const float* __restrict__ x, const float* __restrict__ a,
                   const float* __restrict__ w, const float* __restrict__ beta_u,
                   const float* __restrict__ beta_a, float* __restrict__ out) {
    __shared__ __align__(16) float xp[KB * PS];   // 18 KB patch poses [k][16]
    __shared__ float a_lds[KB];                   // input activations (pre-scaled 1/C)
    __shared__ float buf[8][32][16];              // 16 KB: m1 partials, then m2 partials
    __shared__ float rsp[8][32];                  // partial r_sum
    __shared__ float mu_s[32][16];                // mu    [c][e ^ (c&15)]
    __shared__ float is_s[32][16];                // (0.5/sig^2)*LOG2E, same swizzle
    __shared__ float cst_s[32];                   // (log(ao) - hl)*LOG2E  (log2 domain)
    __shared__ float ao_s[32];                    // a_out of previous iteration

    const int t  = threadIdx.x;       // 512 threads
    const int g  = t >> 5;            // k-group 0..15  (E-step view)
    const int c  = t & 31;            // output capsule (E-step view)
    const int oc = t >> 4;            // capsule 0..31  (M-step view)
    const int oe = t & 15;            // pose elem      (M-step view)

    const int pos = blockIdx.x;
    const int bb  = pos / (OH * OW);
    const int rem = pos % (OH * OW);
    const int hh  = rem / OW;
    const int ww  = rem % OW;

    // ---- stage 3x3 patch into LDS (9 contiguous 2 KB rows, coalesced float4)
    const float4* x4  = (const float4*)x;
    float4*       xp4 = (float4*)xp;
    for (int u = t; u < KB * PS / 4; u += 512) {
        int pc = u >> 7, r = u & 127;
        int ki = pc / 3, kj = pc % 3;
        long src = (((long)(bb * 14 + hh + ki)) * 14 + (ww + kj)) * 128;
        xp4[u] = x4[src + r];
    }
    if (t < KB) {
        int pc = t >> 5, bi = t & 31;
        int ki = pc / 3, kj = pc % 3;
        a_lds[t] = a[(((bb * 14 + hh + ki)) * 14 + (ww + kj)) * 32 + bi] * (1.0f / C_OUT);
    }
    __syncthreads();

    const float buC = beta_u[oc];
    const float baC = beta_a[oc];

    float muR[16], isR[16];           // E-step per-c state (registers)
    float cstC = 0.f;                 // per-c softmax logit constant (log2 domain)
    float U    = 0.f;                 // block-uniform upper bound: max_c cstC

    for (int it = 0; it < NITER; ++it) {
        float m1[16], m2[16], rs = 0.f;
        #pragma unroll
        for (int e = 0; e < 16; ++e) { m1[e] = 0.f; m2[e] = 0.f; }

        if (it == 0) {
            #pragma unroll 2
            for (int kk = 0; kk < KPG; ++kk) {
                int k = g * KPG + kk;
                float va[16];
                compute_v(xp, w, k, c, va);
                float r = a_lds[k];               // already scaled by 1/C
                rs += r;
                #pragma unroll
                for (int e = 0; e < 16; ++e) {
                    float rv = r * va[e];
                    m1[e] += rv;
                    m2[e] = fmaf(rv, va[e], m2[e]);
                }
            }
        } else {
            #pragma unroll 2
            for (int kk = 0; kk < KPG; ++kk) {
                int k = g * KPG + kk;
                float va[16];
                compute_v(xp, w, k, c, va);
                // ln-term (log2 domain), fully lane-local
                float acc = 0.f;
                #pragma unroll
                for (int e = 0; e < 16; ++e) {
                    float d = va[e] - muR[e];
                    acc = fmaf(d * isR[e], d, acc);
                }
                // softmax over c with block-uniform offset U (>= max_c ln, since acc>=0):
                // no per-k max tree needed; exp2 arg <= 0 so no overflow.
                float p = exp2f(fmaxf(cstC - acc - U, -110.0f));
                float sm = p;
                sm += __shfl_xor(sm, 16);
                sm += __shfl_xor(sm, 8);
                sm += __shfl_xor(sm, 4);
                sm += __shfl_xor(sm, 2);
                sm += __shfl_xor(sm, 1);
                float r = p * __builtin_amdgcn_rcpf(sm);   // softmax only; a_out hoisted
                rs += r;
                #pragma unroll
                for (int e = 0; e < 16; ++e) {
                    float rv = r * va[e];
                    m1[e] += rv;
                    m2[e] = fmaf(rv, va[e], m2[e]);
                }
            }
        }

        // ---- reduce over g: in-wave pair reduce, then two-round LDS tree (16 KB buf)
        rs += __shfl_xor(rs, 32);
        #pragma unroll
        for (int e = 0; e < 16; ++e) m1[e] += __shfl_xor(m1[e], 32);
        #pragma unroll
        for (int e = 0; e < 16; ++e) m2[e] += __shfl_xor(m2[e], 32);

        if ((g & 1) == 0) {                       // round A: m1 + rs
            int gp = g >> 1;
            #pragma unroll
            for (int e = 0; e < 16; ++e) buf[gp][c][e ^ (c & 15)] = m1[e];
            rsp[gp][c] = rs;
        }
        __syncthreads();
        float M1 = 0.f, RS = 0.f;
        #pragma unroll
        for (int gp = 0; gp < 8; ++gp) M1 += buf[gp][oc][oe ^ (oc & 15)];
        #pragma unroll
        for (int gp = 0; gp < 8; ++gp) RS += rsp[gp][oc];
        __syncthreads();                          // m1 reads done before m2 overwrite
        if ((g & 1) == 0) {                       // round B: m2
            int gp = g >> 1;
            #pragma unroll
            for (int e = 0; e < 16; ++e) buf[gp][c][e ^ (c & 15)] = m2[e];
        }
        __syncthreads();
        float M2 = 0.f;
        #pragma unroll
        for (int gp = 0; gp < 8; ++gp) M2 += buf[gp][oc][oe ^ (oc & 15)];

        // ---- M-step (oc, oe view); re-apply hoisted a_out factor for it>0
        if (it > 0) {
            float ao_p = ao_s[oc];
            M1 *= ao_p; M2 *= ao_p; RS *= ao_p;
        }
        float inv = __builtin_amdgcn_rcpf(RS + EPSL);
        float muv = M1 * inv;
        float s   = RS * inv;
        float sig = fmaf(-muv * muv, (2.0f - s), M2 * inv) + EPSL;
        float hl  = 0.5f * __logf(sig);           // natural log (for cost)
        hl += __shfl_xor(hl, 1);
        hl += __shfl_xor(hl, 2);
        hl += __shfl_xor(hl, 4);
        hl += __shfl_xor(hl, 8);
        float cost = RS * fmaf(16.0f, buC, hl);
        float ao   = 1.0f / (1.0f + __expf(-LAM * (baC - cost)));

        if (it == NITER - 1) {
            out[pos * 512 + t] = muv;                    // t == oc*16+oe
            if (oe == 0) out[MU_SZ + pos * 32 + oc] = ao;
        } else {
            mu_s[oc][oe ^ (oc & 15)] = muv;
            is_s[oc][oe ^ (oc & 15)] = (0.5f / sig) * LOG2E;
            if (oe == 0) {
                cst_s[oc] = (__logf(ao) - hl) * LOG2E;   // log2-domain logit constant
                ao_s[oc]  = ao;
            }
            __syncthreads();
            // back in (g,c) view: pull next-iteration E-state into registers
            #pragma unroll
            for (int e = 0; e < 16; ++e) muR[e] = mu_s[c][e ^ (c & 15)];
            #pragma unroll
            for (int e = 0; e < 16; ++e) isR[e] = is_s[c][e ^ (c & 15)];
            cstC = cst_s[c];
            // U = max_c cst: 5 shuffles ONCE per iteration (replaces per-k max tree)
            U = cstC;
            U = fmaxf(U, __shfl_xor(U, 16));
            U = fmaxf(U, __shfl_xor(U, 8));
            U = fmaxf(U, __shfl_xor(U, 4));
            U = fmaxf(U, __shfl_xor(U, 2));
            U = fmaxf(U, __shfl_xor(U, 1));
        }
    }
}

extern "C" void kernel_launch(void* const* d_in, const int* in_sizes, int n_in,
                              void* d_out, int out_size, void* d_ws, size_t ws_size,
                              hipStream_t stream) {
    const float* x  = (const float*)d_in[0];
    const float* a  = (const float*)d_in[1];
    const float* w  = (const float*)d_in[2];
    const float* bu = (const float*)d_in[3];
    const float* ba = (const float*)d_in[4];
    float* out = (float*)d_out;
    emcaps_kernel<<<NPOS, 512, 0, stream>>>(x, a, w, bu, ba, out);
}

// Round 10
// 164.924 us; speedup vs baseline: 1.3417x; 1.0289x over previous
//
#include <hip/hip_runtime.h>

#define C_OUT  32
#define PS     16
#define KB     288          // 3*3*32 input capsules per patch
#define NITER  3
#define EPSL   1e-6f
#define LAM    0.001f
#define OH     12
#define OW     12
#define NPOS   576          // 4*12*12
#define MU_SZ  (NPOS*C_OUT*PS)
#define NG     16           // k-groups (one per 32-lane half-wave)
#define KPG    (KB/NG)      // 18 k's per thread
#define LOG2E  1.44269504088896340736f

// ---- DPP row-rotation reductions: all-lanes row(16) sum/max in 4 VALU ops,
// no DS pipe. row_ror:n ctrl = 0x120+n. GCNDPPCombine folds mov_dpp into the
// consumer v_add/v_max. Rotation assoc order differs per lane (last-ulp only).
#define DPP_ROR(x, n) __int_as_float(__builtin_amdgcn_update_dpp( \
        0, __float_as_int(x), 0x120 + (n), 0xF, 0xF, true))

__device__ __forceinline__ float dpp_sum16(float x) {
    x += DPP_ROR(x, 1);
    x += DPP_ROR(x, 2);
    x += DPP_ROR(x, 4);
    x += DPP_ROR(x, 8);
    return x;                       // every lane: sum of its 16-lane row
}
__device__ __forceinline__ float dpp_max16(float x) {
    x = fmaxf(x, DPP_ROR(x, 1));
    x = fmaxf(x, DPP_ROR(x, 2));
    x = fmaxf(x, DPP_ROR(x, 4));
    x = fmaxf(x, DPP_ROR(x, 8));
    return x;
}

// v[k,c,i,l] = sum_j xp[k,i,j] * w[k,c,j,l]  — full 4x4 matrix per (k,c) in registers.
__device__ __forceinline__ void compute_v(const float* __restrict__ xp,
                                          const float* __restrict__ w,
                                          int k, int c, float* __restrict__ va) {
    const float4* xk = (const float4*)(xp + (k << 4));
    float4 x0 = xk[0], x1 = xk[1], x2 = xk[2], x3 = xk[3];   // row i over j
    const float4* wr = (const float4*)(w + (((k << 5) + c) << 4));
    float4 w0 = wr[0], w1 = wr[1], w2 = wr[2], w3 = wr[3];   // row j over l
#define VROW(i, xi) \
    va[4*i+0] = fmaf(xi.x, w0.x, fmaf(xi.y, w1.x, fmaf(xi.z, w2.x, xi.w * w3.x))); \
    va[4*i+1] = fmaf(xi.x, w0.y, fmaf(xi.y, w1.y, fmaf(xi.z, w2.y, xi.w * w3.y))); \
    va[4*i+2] = fmaf(xi.x, w0.z, fmaf(xi.y, w1.z, fmaf(xi.z, w2.z, xi.w * w3.z))); \
    va[4*i+3] = fmaf(xi.x, w0.w, fmaf(xi.y, w1.w, fmaf(xi.z, w2.w, xi.w * w3.w)));
    VROW(0, x0) VROW(1, x1) VROW(2, x2) VROW(3, x3)
#undef VROW
}

// (512,2): allocator takes ~120 VGPR with zero spill. Forcing higher occupancy
// spilled 1.5 GB to scratch (rounds 2-3). Must stay <=128 VGPR (wave cliff).
__global__ __launch_bounds__(512, 2)
void emcaps_kernel(const float* __restrict__ x, const float* __restrict__ a,
                   const float* __restrict__ w, const float* __restrict__ beta_u,
                   const float* __restrict__ beta_a, float* __restrict__ out) {
    __shared__ __align__(16) float xp[KB * PS];   // 18 KB patch poses [k][16]
    __shared__ float a_lds[KB];                   // input activations (pre-scaled 1/C)
    __shared__ float buf[8][32][16];              // 16 KB: m1 partials, then m2 partials
    __shared__ float rsp[8][32];                  // partial r_sum
    __shared__ float mu_s[32][16];                // mu    [c][e ^ (c&15)]
    __shared__ float is_s[32][16];                // (0.5/sig^2)*LOG2E, same swizzle
    __shared__ float cst_s[32];                   // (log(ao) - hl)*LOG2E  (log2 domain)
    __shared__ float ao_s[32];                    // a_out of previous iteration

    const int t  = threadIdx.x;       // 512 threads
    const int g  = t >> 5;            // k-group 0..15  (E-step view)
    const int c  = t & 31;            // output capsule (E-step view)
    const int oc = t >> 4;            // capsule 0..31  (M-step view)
    const int oe = t & 15;            // pose elem      (M-step view)

    const int pos = blockIdx.x;
    const int bb  = pos / (OH * OW);
    const int rem = pos % (OH * OW);
    const int hh  = rem / OW;
    const int ww  = rem % OW;

    // ---- stage 3x3 patch into LDS (9 contiguous 2 KB rows, coalesced float4)
    const float4* x4  = (const float4*)x;
    float4*       xp4 = (float4*)xp;
    for (int u = t; u < KB * PS / 4; u += 512) {
        int pc = u >> 7, r = u & 127;
        int ki = pc / 3, kj = pc % 3;
        long src = (((long)(bb * 14 + hh + ki)) * 14 + (ww + kj)) * 128;
        xp4[u] = x4[src + r];
    }
    if (t < KB) {
        int pc = t >> 5, bi = t & 31;
        int ki = pc / 3, kj = pc % 3;
        a_lds[t] = a[(((bb * 14 + hh + ki)) * 14 + (ww + kj)) * 32 + bi] * (1.0f / C_OUT);
    }
    __syncthreads();

    const float buC = beta_u[oc];
    const float baC = beta_a[oc];

    float muR[16], isR[16];           // E-step per-c state (registers)
    float cstC = 0.f;                 // per-c softmax logit constant (log2 domain)
    float U    = 0.f;                 // block-uniform upper bound: max_c cstC

    for (int it = 0; it < NITER; ++it) {
        float m1[16], m2[16], rs = 0.f;
        #pragma unroll
        for (int e = 0; e < 16; ++e) { m1[e] = 0.f; m2[e] = 0.f; }

        if (it == 0) {
            #pragma unroll 2
            for (int kk = 0; kk < KPG; ++kk) {
                int k = g * KPG + kk;
                float va[16];
                compute_v(xp, w, k, c, va);
                float r = a_lds[k];               // already scaled by 1/C
                rs += r;
                #pragma unroll
                for (int e = 0; e < 16; ++e) {
                    float rv = r * va[e];
                    m1[e] += rv;
                    m2[e] = fmaf(rv, va[e], m2[e]);
                }
            }
        } else {
            #pragma unroll 2
            for (int kk = 0; kk < KPG; ++kk) {
                int k = g * KPG + kk;
                float va[16];
                compute_v(xp, w, k, c, va);
                // ln-term (log2 domain), fully lane-local
                float acc = 0.f;
                #pragma unroll
                for (int e = 0; e < 16; ++e) {
                    float d = va[e] - muR[e];
                    acc = fmaf(d * isR[e], d, acc);
                }
                // softmax over c with block-uniform offset U (>= max_c ln since acc>=0)
                float p = exp2f(fmaxf(cstC - acc - U, -110.0f));
                // sum over 32 c-lanes: 4 DPP-VALU adds + one xor16 hop
                float sm = dpp_sum16(p);
                sm += __shfl_xor(sm, 16);
                float r = p * __builtin_amdgcn_rcpf(sm);   // a_out hoisted to M-step
                rs += r;
                #pragma unroll
                for (int e = 0; e < 16; ++e) {
                    float rv = r * va[e];
                    m1[e] += rv;
                    m2[e] = fmaf(rv, va[e], m2[e]);
                }
            }
        }

        // ---- reduce over g: in-wave pair reduce, then two-round LDS tree (16 KB buf)
        rs += __shfl_xor(rs, 32);
        #pragma unroll
        for (int e = 0; e < 16; ++e) m1[e] += __shfl_xor(m1[e], 32);
        #pragma unroll
        for (int e = 0; e < 16; ++e) m2[e] += __shfl_xor(m2[e], 32);

        if ((g & 1) == 0) {                       // round A: m1 + rs
            int gp = g >> 1;
            #pragma unroll
            for (int e = 0; e < 16; ++e) buf[gp][c][e ^ (c & 15)] = m1[e];
            rsp[gp][c] = rs;
        }
        __syncthreads();
        float M1 = 0.f, RS = 0.f;
        #pragma unroll
        for (int gp = 0; gp < 8; ++gp) M1 += buf[gp][oc][oe ^ (oc & 15)];
        #pragma unroll
        for (int gp = 0; gp < 8; ++gp) RS += rsp[gp][oc];
        __syncthreads();                          // m1 reads done before m2 overwrite
        if ((g & 1) == 0) {                       // round B: m2
            int gp = g >> 1;
            #pragma unroll
            for (int e = 0; e < 16; ++e) buf[gp][c][e ^ (c & 15)] = m2[e];
        }
        __syncthreads();
        float M2 = 0.f;
        #pragma unroll
        for (int gp = 0; gp < 8; ++gp) M2 += buf[gp][oc][oe ^ (oc & 15)];

        // ---- M-step (oc, oe view); re-apply hoisted a_out factor for it>0
        if (it > 0) {
            float ao_p = ao_s[oc];
            M1 *= ao_p; M2 *= ao_p; RS *= ao_p;
        }
        float inv = __builtin_amdgcn_rcpf(RS + EPSL);
        float muv = M1 * inv;
        float s   = RS * inv;
        float sig = fmaf(-muv * muv, (2.0f - s), M2 * inv) + EPSL;
        // Sum_e 0.5*log(sig) over the 16-lane row: pure DPP, zero DS ops
        float hl  = dpp_sum16(0.5f * __logf(sig));
        float cost = RS * fmaf(16.0f, buC, hl);
        float ao   = 1.0f / (1.0f + __expf(-LAM * (baC - cost)));

        if (it == NITER - 1) {
            out[pos * 512 + t] = muv;                    // t == oc*16+oe
            if (oe == 0) out[MU_SZ + pos * 32 + oc] = ao;
        } else {
            mu_s[oc][oe ^ (oc & 15)] = muv;
            is_s[oc][oe ^ (oc & 15)] = (0.5f / sig) * LOG2E;
            if (oe == 0) {
                cst_s[oc] = (__logf(ao) - hl) * LOG2E;   // log2-domain logit constant
                ao_s[oc]  = ao;
            }
            __syncthreads();
            // back in (g,c) view: pull next-iteration E-state into registers
            #pragma unroll
            for (int e = 0; e < 16; ++e) muR[e] = mu_s[c][e ^ (c & 15)];
            #pragma unroll
            for (int e = 0; e < 16; ++e) isR[e] = is_s[c][e ^ (c & 15)];
            cstC = cst_s[c];
            // U = max_c cst: once per iteration (replaces per-k max tree)
            U = dpp_max16(cstC);
            U = fmaxf(U, __shfl_xor(U, 16));
        }
    }
}

extern "C" void kernel_launch(void* const* d_in, const int* in_sizes, int n_in,
                              void* d_out, int out_size, void* d_ws, size_t ws_size,
                              hipStream_t stream) {
    const float* x  = (const float*)d_in[0];
    const float* a  = (const float*)d_in[1];
    const float* w  = (const float*)d_in[2];
    const float* bu = (const float*)d_in[3];
    const float* ba = (const float*)d_in[4];
    float* out = (float*)d_out;
    emcaps_kernel<<<NPOS, 512, 0, stream>>>(x, a, w, bu, ba, out);
}

// Round 11
// 160.511 us; speedup vs baseline: 1.3786x; 1.0275x over previous
//
#include <hip/hip_runtime.h>

#define C_OUT  32
#define PS     16
#define KB     288          // 3*3*32 input capsules per patch
#define NITER  3
#define EPSL   1e-6f
#define LAM    0.001f
#define OH     12
#define OW     12
#define NPOS   576          // 4*12*12
#define MU_SZ  (NPOS*C_OUT*PS)
#define NG     16           // k-groups (one per 32-lane half-wave)
#define KPG    (KB/NG)      // 18 k's per thread
#define LOG2E  1.44269504088896340736f

typedef float v2f __attribute__((ext_vector_type(2)));   // -> v_pk_*_f32

// ---- DPP row-rotation reductions (VALU, no DS pipe)
#define DPP_ROR(x, n) __int_as_float(__builtin_amdgcn_update_dpp( \
        0, __float_as_int(x), 0x120 + (n), 0xF, 0xF, true))

__device__ __forceinline__ float dpp_sum16(float x) {
    x += DPP_ROR(x, 1);
    x += DPP_ROR(x, 2);
    x += DPP_ROR(x, 4);
    x += DPP_ROR(x, 8);
    return x;
}
__device__ __forceinline__ float dpp_max16(float x) {
    x = fmaxf(x, DPP_ROR(x, 1));
    x = fmaxf(x, DPP_ROR(x, 2));
    x = fmaxf(x, DPP_ROR(x, 4));
    x = fmaxf(x, DPP_ROR(x, 8));
    return x;
}

// v[k,c,i,:] as 8 packed l-pairs: va2[2i+p] = (v[i,2p], v[i,2p+1]).
// 32 v_pk_fma_f32 instead of 64 v_fma_f32.
__device__ __forceinline__ void compute_v2(const float* __restrict__ xp,
                                           const float* __restrict__ w,
                                           int k, int c, v2f* __restrict__ va2) {
    const float4* xk = (const float4*)(xp + (k << 4));
    float4 x0 = xk[0], x1 = xk[1], x2 = xk[2], x3 = xk[3];   // row i over j
    const v2f* wr = (const v2f*)(w + (((k << 5) + c) << 4));
    v2f w0a = wr[0], w0b = wr[1], w1a = wr[2], w1b = wr[3];  // row j: (l0,l1),(l2,l3)
    v2f w2a = wr[4], w2b = wr[5], w3a = wr[6], w3b = wr[7];
#define VROW2(i, xi) \
    va2[2*i]   = (w0a * xi.x + w1a * xi.y) + (w2a * xi.z + w3a * xi.w); \
    va2[2*i+1] = (w0b * xi.x + w1b * xi.y) + (w2b * xi.z + w3b * xi.w);
    VROW2(0, x0) VROW2(1, x1) VROW2(2, x2) VROW2(3, x3)
#undef VROW2
}

// (512,2): allocator takes ~120 VGPR, zero spill. MUST stay <=128 (wave cliff);
// forcing higher occupancy spilled 1.5 GB to scratch (rounds 2-3).
__global__ __launch_bounds__(512, 2)
void emcaps_kernel(const float* __restrict__ x, const float* __restrict__ a,
                   const float* __restrict__ w, const float* __restrict__ beta_u,
                   const float* __restrict__ beta_a, float* __restrict__ out) {
    __shared__ __align__(16) float xp[KB * PS];   // 18 KB patch poses [k][16]
    __shared__ float a_lds[KB];                   // input activations (pre-scaled 1/C)
    __shared__ float buf[8][32][16];              // 16 KB: m1 partials, then m2 partials
    __shared__ float rsp[8][32];                  // partial r_sum
    __shared__ float mu_s[32][16];                // mu    [c][e ^ (c&15)]
    __shared__ float is_s[32][16];                // (0.5/sig^2)*LOG2E, same swizzle
    __shared__ float cst_s[32];                   // (log(ao) - hl)*LOG2E  (log2 domain)
    __shared__ float ao_s[32];                    // a_out of previous iteration

    const int t  = threadIdx.x;       // 512 threads
    const int g  = t >> 5;            // k-group 0..15  (E-step view)
    const int c  = t & 31;            // output capsule (E-step view)
    const int oc = t >> 4;            // capsule 0..31  (M-step view)
    const int oe = t & 15;            // pose elem      (M-step view)

    const int pos = blockIdx.x;
    const int bb  = pos / (OH * OW);
    const int rem = pos % (OH * OW);
    const int hh  = rem / OW;
    const int ww  = rem % OW;

    // ---- stage 3x3 patch into LDS (9 contiguous 2 KB rows, coalesced float4)
    const float4* x4  = (const float4*)x;
    float4*       xp4 = (float4*)xp;
    for (int u = t; u < KB * PS / 4; u += 512) {
        int pc = u >> 7, r = u & 127;
        int ki = pc / 3, kj = pc % 3;
        long src = (((long)(bb * 14 + hh + ki)) * 14 + (ww + kj)) * 128;
        xp4[u] = x4[src + r];
    }
    if (t < KB) {
        int pc = t >> 5, bi = t & 31;
        int ki = pc / 3, kj = pc % 3;
        a_lds[t] = a[(((bb * 14 + hh + ki)) * 14 + (ww + kj)) * 32 + bi] * (1.0f / C_OUT);
    }
    __syncthreads();

    const float buC = beta_u[oc];
    const float baC = beta_a[oc];

    v2f  mu2[8], is2[8];              // E-step per-c state, packed over e-pairs
    float cstC = 0.f;                 // per-c softmax logit constant (log2 domain)
    float U    = 0.f;                 // block-uniform upper bound: max_c cstC

    for (int it = 0; it < NITER; ++it) {
        v2f m1[8], m2[8];
        float rs = 0.f;
        #pragma unroll
        for (int ep = 0; ep < 8; ++ep) { m1[ep] = (v2f)0.f; m2[ep] = (v2f)0.f; }

        if (it == 0) {
            #pragma unroll 2
            for (int kk = 0; kk < KPG; ++kk) {
                int k = g * KPG + kk;
                v2f va2[8];
                compute_v2(xp, w, k, c, va2);
                float r = a_lds[k];               // already scaled by 1/C
                rs += r;
                #pragma unroll
                for (int ep = 0; ep < 8; ++ep) {
                    v2f rv = va2[ep] * r;
                    m1[ep] += rv;
                    m2[ep] += rv * va2[ep];
                }
            }
        } else {
            #pragma unroll 2
            for (int kk = 0; kk < KPG; ++kk) {
                int k = g * KPG + kk;
                v2f va2[8];
                compute_v2(xp, w, k, c, va2);
                // ln-term (log2 domain), packed then horizontal
                v2f acc2 = (v2f)0.f;
                #pragma unroll
                for (int ep = 0; ep < 8; ++ep) {
                    v2f d = va2[ep] - mu2[ep];
                    acc2 += (d * is2[ep]) * d;
                }
                float acc = acc2.x + acc2.y;
                // softmax over c with block-uniform offset U (>= max_c ln since acc>=0)
                float p = exp2f(fmaxf(cstC - acc - U, -110.0f));
                float sm = dpp_sum16(p);
                sm += __shfl_xor(sm, 16);
                float r = p * __builtin_amdgcn_rcpf(sm);   // a_out hoisted to M-step
                rs += r;
                #pragma unroll
                for (int ep = 0; ep < 8; ++ep) {
                    v2f rv = va2[ep] * r;
                    m1[ep] += rv;
                    m2[ep] += rv * va2[ep];
                }
            }
        }

        // ---- reduce over g: in-wave pair reduce, then two-round LDS tree (16 KB buf)
        rs += __shfl_xor(rs, 32);
        #pragma unroll
        for (int ep = 0; ep < 8; ++ep) {
            m1[ep].x += __shfl_xor(m1[ep].x, 32);
            m1[ep].y += __shfl_xor(m1[ep].y, 32);
            m2[ep].x += __shfl_xor(m2[ep].x, 32);
            m2[ep].y += __shfl_xor(m2[ep].y, 32);
        }

        if ((g & 1) == 0) {                       // round A: m1 + rs
            int gp = g >> 1;
            #pragma unroll
            for (int ep = 0; ep < 8; ++ep) {
                buf[gp][c][(2*ep)     ^ (c & 15)] = m1[ep].x;
                buf[gp][c][(2*ep + 1) ^ (c & 15)] = m1[ep].y;
            }
            rsp[gp][c] = rs;
        }
        __syncthreads();
        float M1 = 0.f, RS = 0.f;
        #pragma unroll
        for (int gp = 0; gp < 8; ++gp) M1 += buf[gp][oc][oe ^ (oc & 15)];
        #pragma unroll
        for (int gp = 0; gp < 8; ++gp) RS += rsp[gp][oc];
        __syncthreads();                          // m1 reads done before m2 overwrite
        if ((g & 1) == 0) {                       // round B: m2
            int gp = g >> 1;
            #pragma unroll
            for (int ep = 0; ep < 8; ++ep) {
                buf[gp][c][(2*ep)     ^ (c & 15)] = m2[ep].x;
                buf[gp][c][(2*ep + 1) ^ (c & 15)] = m2[ep].y;
            }
        }
        __syncthreads();
        float M2 = 0.f;
        #pragma unroll
        for (int gp = 0; gp < 8; ++gp) M2 += buf[gp][oc][oe ^ (oc & 15)];

        // ---- M-step (oc, oe view); re-apply hoisted a_out factor for it>0
        if (it > 0) {
            float ao_p = ao_s[oc];
            M1 *= ao_p; M2 *= ao_p; RS *= ao_p;
        }
        float inv = __builtin_amdgcn_rcpf(RS + EPSL);
        float muv = M1 * inv;
        float s   = RS * inv;
        float sig = fmaf(-muv * muv, (2.0f - s), M2 * inv) + EPSL;
        float hl  = dpp_sum16(0.5f * __logf(sig));    // Sum_e over 16-lane row, pure DPP
        float cost = RS * fmaf(16.0f, buC, hl);
        float ao   = 1.0f / (1.0f + __expf(-LAM * (baC - cost)));

        if (it == NITER - 1) {
            out[pos * 512 + t] = muv;                    // t == oc*16+oe
            if (oe == 0) out[MU_SZ + pos * 32 + oc] = ao;
        } else {
            mu_s[oc][oe ^ (oc & 15)] = muv;
            is_s[oc][oe ^ (oc & 15)] = (0.5f / sig) * LOG2E;
            if (oe == 0) {
                cst_s[oc] = (__logf(ao) - hl) * LOG2E;   // log2-domain logit constant
                ao_s[oc]  = ao;
            }
            __syncthreads();
            // back in (g,c) view: pull next-iteration E-state into packed registers
            #pragma unroll
            for (int ep = 0; ep < 8; ++ep) {
                mu2[ep].x = mu_s[c][(2*ep)     ^ (c & 15)];
                mu2[ep].y = mu_s[c][(2*ep + 1) ^ (c & 15)];
                is2[ep].x = is_s[c][(2*ep)     ^ (c & 15)];
                is2[ep].y = is_s[c][(2*ep + 1) ^ (c & 15)];
            }
            cstC = cst_s[c];
            // U = max_c cst: once per iteration
            U = dpp_max16(cstC);
            U = fmaxf(U, __shfl_xor(U, 16));
        }
    }
}

extern "C" void kernel_launch(void* const* d_in, const int* in_sizes, int n_in,
                              void* d_out, int out_size, void* d_ws, size_t ws_size,
                              hipStream_t stream) {
    const float* x  = (const float*)d_in[0];
    const float* a  = (const float*)d_in[1];
    const float* w  = (const float*)d_in[2];
    const float* bu = (const float*)d_in[3];
    const float* ba = (const float*)d_in[4];
    float* out = (float*)d_out;
    emcaps_kernel<<<NPOS, 512, 0, stream>>>(x, a, w, bu, ba, out);
}

// Round 14
// 157.852 us; speedup vs baseline: 1.4018x; 1.0168x over previous
//
#include <hip/hip_runtime.h>

#define C_OUT  32
#define PS     16
#define KB     288          // 3*3*32 input capsules per patch
#define NITER  3
#define EPSL   1e-6f
#define LAM    0.001f
#define OH     12
#define OW     12
#define NPOS   576          // 4*12*12
#define MU_SZ  (NPOS*C_OUT*PS)
#define NTHR   256          // 4-wave blocks: 3-4 blocks/CU co-resident (no serial tail)
#define NG     8            // k-groups
#define KPG    (KB/NG)      // 36 k's per thread
#define LOG2E  1.44269504088896340736f

typedef float v2f __attribute__((ext_vector_type(2)));   // -> v_pk_*_f32

// ---- DPP row-rotation reductions (VALU, no DS pipe)
#define DPP_ROR(x, n) __int_as_float(__builtin_amdgcn_update_dpp( \
        0, __float_as_int(x), 0x120 + (n), 0xF, 0xF, true))

__device__ __forceinline__ float dpp_sum16(float x) {
    x += DPP_ROR(x, 1);
    x += DPP_ROR(x, 2);
    x += DPP_ROR(x, 4);
    x += DPP_ROR(x, 8);
    return x;
}
__device__ __forceinline__ float dpp_max16(float x) {
    x = fmaxf(x, DPP_ROR(x, 1));
    x = fmaxf(x, DPP_ROR(x, 2));
    x = fmaxf(x, DPP_ROR(x, 4));
    x = fmaxf(x, DPP_ROR(x, 8));
    return x;
}

// v[k,c,i,:] as 8 packed l-pairs (v_pk_fma_f32 path)
__device__ __forceinline__ void compute_v2(const float* __restrict__ xp,
                                           const float* __restrict__ w,
                                           int k, int c, v2f* __restrict__ va2) {
    const float4* xk = (const float4*)(xp + (k << 4));
    float4 x0 = xk[0], x1 = xk[1], x2 = xk[2], x3 = xk[3];   // row i over j
    const v2f* wr = (const v2f*)(w + (((k << 5) + c) << 4));
    v2f w0a = wr[0], w0b = wr[1], w1a = wr[2], w1b = wr[3];  // row j: (l0,l1),(l2,l3)
    v2f w2a = wr[4], w2b = wr[5], w3a = wr[6], w3b = wr[7];
#define VROW2(i, xi) \
    va2[2*i]   = (w0a * xi.x + w1a * xi.y) + (w2a * xi.z + w3a * xi.w); \
    va2[2*i+1] = (w0b * xi.x + w1b * xi.y) + (w2b * xi.z + w3b * xi.w);
    VROW2(0, x0) VROW2(1, x1) VROW2(2, x2) VROW2(3, x3)
#undef VROW2
}

// (256,3): 4-wave blocks; guarantees >=3 waves/SIMD (>=3 blocks/CU) without
// forcing the allocator below its ~120-reg need (VGPR cap 170 -> no spill).
__global__ __launch_bounds__(NTHR, 3)
void emcaps_kernel(const float* __restrict__ x, const float* __restrict__ a,
                   const float* __restrict__ w, const float* __restrict__ beta_u,
                   const float* __restrict__ beta_a, float* __restrict__ out) {
    __shared__ __align__(16) float xp[KB * PS];   // 18 KB patch poses [k][16]
    __shared__ float a_lds[KB];                   // input activations (pre-scaled 1/C)
    __shared__ float buf[4][32][16];              // 8 KB: m1 partials, then m2 partials
    __shared__ float rsp[4][32];                  // partial r_sum
    __shared__ float mu_s[32][16];                // mu    [c][e ^ (c&15)]
    __shared__ float is_s[32][16];                // (0.5/sig^2)*LOG2E, same swizzle
    __shared__ float cst_s[32];                   // (log(ao) - hl)*LOG2E  (log2 domain)
    __shared__ float ao_s[32];                    // a_out of previous iteration

    const int t  = threadIdx.x;       // 256 threads
    const int g  = t >> 5;            // k-group 0..7   (E-step view)
    const int c  = t & 31;            // output capsule (E-step view)
    const int oc = t >> 4;            // capsule 0..15  (M-step view; also handles oc+16)
    const int oe = t & 15;            // pose elem      (M-step view)

    const int pos = blockIdx.x;
    const int bb  = pos / (OH * OW);
    const int rem = pos % (OH * OW);
    const int hh  = rem / OW;
    const int ww  = rem % OW;

    // ---- stage 3x3 patch into LDS (9 contiguous 2 KB rows, coalesced float4)
    const float4* x4  = (const float4*)x;
    float4*       xp4 = (float4*)xp;
    for (int u = t; u < KB * PS / 4; u += NTHR) {
        int pc = u >> 7, r = u & 127;
        int ki = pc / 3, kj = pc % 3;
        long src = (((long)(bb * 14 + hh + ki)) * 14 + (ww + kj)) * 128;
        xp4[u] = x4[src + r];
    }
    for (int u = t; u < KB; u += NTHR) {
        int pc = u >> 5, bi = u & 31;
        int ki = pc / 3, kj = pc % 3;
        a_lds[u] = a[(((bb * 14 + hh + ki)) * 14 + (ww + kj)) * 32 + bi] * (1.0f / C_OUT);
    }
    __syncthreads();

    const float buCa = beta_u[oc],  baCa = beta_a[oc];
    const float buCb = beta_u[oc + 16], baCb = beta_a[oc + 16];

    v2f  mu2[8], is2[8];              // E-step per-c state, packed over e-pairs
    float cstC = 0.f;                 // per-c softmax logit constant (log2 domain)
    float U    = 0.f;                 // block-uniform upper bound: max_c cstC

    for (int it = 0; it < NITER; ++it) {
        v2f m1[8], m2[8];
        float rs = 0.f;
        #pragma unroll
        for (int ep = 0; ep < 8; ++ep) { m1[ep] = (v2f)0.f; m2[ep] = (v2f)0.f; }

        if (it == 0) {
            #pragma unroll 2
            for (int kk = 0; kk < KPG; ++kk) {
                int k = g * KPG + kk;
                v2f va2[8];
                compute_v2(xp, w, k, c, va2);
                float r = a_lds[k];               // already scaled by 1/C
                rs += r;
                #pragma unroll
                for (int ep = 0; ep < 8; ++ep) {
                    v2f rv = va2[ep] * r;
                    m1[ep] += rv;
                    m2[ep] += rv * va2[ep];
                }
            }
        } else {
            #pragma unroll 2
            for (int kk = 0; kk < KPG; ++kk) {
                int k = g * KPG + kk;
                v2f va2[8];
                compute_v2(xp, w, k, c, va2);
                v2f acc2 = (v2f)0.f;
                #pragma unroll
                for (int ep = 0; ep < 8; ++ep) {
                    v2f d = va2[ep] - mu2[ep];
                    acc2 += (d * is2[ep]) * d;
                }
                float acc = acc2.x + acc2.y;
                // softmax over c with block-uniform offset U (>= max_c ln since acc>=0)
                float p = exp2f(fmaxf(cstC - acc - U, -110.0f));
                float sm = dpp_sum16(p);
                sm += __shfl_xor(sm, 16);
                float r = p * __builtin_amdgcn_rcpf(sm);   // a_out hoisted to M-step
                rs += r;
                #pragma unroll
                for (int ep = 0; ep < 8; ++ep) {
                    v2f rv = va2[ep] * r;
                    m1[ep] += rv;
                    m2[ep] += rv * va2[ep];
                }
            }
        }

        // ---- reduce over g: in-wave pair reduce (xor32), then LDS tree (4 partials)
        rs += __shfl_xor(rs, 32);
        #pragma unroll
        for (int ep = 0; ep < 8; ++ep) {
            m1[ep].x += __shfl_xor(m1[ep].x, 32);
            m1[ep].y += __shfl_xor(m1[ep].y, 32);
            m2[ep].x += __shfl_xor(m2[ep].x, 32);
            m2[ep].y += __shfl_xor(m2[ep].y, 32);
        }

        if ((g & 1) == 0) {                       // round A: m1 + rs
            int gp = g >> 1;
            #pragma unroll
            for (int ep = 0; ep < 8; ++ep) {
                buf[gp][c][(2*ep)     ^ (c & 15)] = m1[ep].x;
                buf[gp][c][(2*ep + 1) ^ (c & 15)] = m1[ep].y;
            }
            rsp[gp][c] = rs;
        }
        __syncthreads();
        float M1a = 0.f, RSa = 0.f, M1b = 0.f, RSb = 0.f;
        #pragma unroll
        for (int gp = 0; gp < 4; ++gp) {
            M1a += buf[gp][oc][oe ^ (oc & 15)];
            M1b += buf[gp][oc + 16][oe ^ (oc & 15)];
            RSa += rsp[gp][oc];
            RSb += rsp[gp][oc + 16];
        }
        __syncthreads();                          // m1 reads done before m2 overwrite
        if ((g & 1) == 0) {                       // round B: m2
            int gp = g >> 1;
            #pragma unroll
            for (int ep = 0; ep < 8; ++ep) {
                buf[gp][c][(2*ep)     ^ (c & 15)] = m2[ep].x;
                buf[gp][c][(2*ep + 1) ^ (c & 15)] = m2[ep].y;
            }
        }
        __syncthreads();
        float M2a = 0.f, M2b = 0.f;
        #pragma unroll
        for (int gp = 0; gp < 4; ++gp) {
            M2a += buf[gp][oc][oe ^ (oc & 15)];
            M2b += buf[gp][oc + 16][oe ^ (oc & 15)];
        }

        // ---- M-step for capsule oc (a) and oc+16 (b)
        if (it > 0) {
            float aoa = ao_s[oc], aob = ao_s[oc + 16];
            M1a *= aoa; M2a *= aoa; RSa *= aoa;
            M1b *= aob; M2b *= aob; RSb *= aob;
        }
        float inva = __builtin_amdgcn_rcpf(RSa + EPSL);
        float invb = __builtin_amdgcn_rcpf(RSb + EPSL);
        float muva = M1a * inva,            muvb = M1b * invb;
        float sa   = RSa * inva,            sb   = RSb * invb;
        float siga = fmaf(-muva * muva, (2.0f - sa), M2a * inva) + EPSL;
        float sigb = fmaf(-muvb * muvb, (2.0f - sb), M2b * invb) + EPSL;
        float hla  = dpp_sum16(0.5f * __logf(siga));   // row = (oc, e 0..15)
        float hlb  = dpp_sum16(0.5f * __logf(sigb));
        float costa = RSa * fmaf(16.0f, buCa, hla);
        float costb = RSb * fmaf(16.0f, buCb, hlb);
        float aoa   = 1.0f / (1.0f + __expf(-LAM * (baCa - costa)));
        float aob   = 1.0f / (1.0f + __expf(-LAM * (baCb - costb)));

        if (it == NITER - 1) {
            out[pos * 512 + t]       = muva;             // (oc)   *16+oe == t
            out[pos * 512 + 256 + t] = muvb;             // (oc+16)*16+oe == 256+t
            if (oe == 0) {
                out[MU_SZ + pos * 32 + oc]      = aoa;
                out[MU_SZ + pos * 32 + oc + 16] = aob;
            }
        } else {
            mu_s[oc][oe ^ (oc & 15)]      = muva;
            mu_s[oc + 16][oe ^ (oc & 15)] = muvb;
            is_s[oc][oe ^ (oc & 15)]      = (0.5f / siga) * LOG2E;
            is_s[oc + 16][oe ^ (oc & 15)] = (0.5f / sigb) * LOG2E;
            if (oe == 0) {
                cst_s[oc]      = (__logf(aoa) - hla) * LOG2E;
                cst_s[oc + 16] = (__logf(aob) - hlb) * LOG2E;
                ao_s[oc]       = aoa;
                ao_s[oc + 16]  = aob;
            }
            __syncthreads();
            // back in (g,c) view: pull next-iteration E-state into packed registers
            #pragma unroll
            for (int ep = 0; ep < 8; ++ep) {
                mu2[ep].x = mu_s[c][(2*ep)     ^ (c & 15)];
                mu2[ep].y = mu_s[c][(2*ep + 1) ^ (c & 15)];
                is2[ep].x = is_s[c][(2*ep)     ^ (c & 15)];
                is2[ep].y = is_s[c][(2*ep + 1) ^ (c & 15)];
            }
            cstC = cst_s[c];
            U = dpp_max16(cstC);
            U = fmaxf(U, __shfl_xor(U, 16));
        }
    }
}

extern "C" void kernel_launch(void* const* d_in, const int* in_sizes, int n_in,
                              void* d_out, int out_size, void* d_ws, size_t ws_size,
                              hipStream_t stream) {
    const float* x  = (const float*)d_in[0];
    const float* a  = (const float*)d_in[1];
    const float* w  = (const float*)d_in[2];
    const float* bu = (const float*)d_in[3];
    const float* ba = (const float*)d_in[4];
    float* out = (float*)d_out;
    emcaps_kernel<<<NPOS, NTHR, 0, stream>>>(x, a, w, bu, ba, out);
}